// Round 1
// baseline (50.619 us; speedup 1.0000x reference)
//
#include <hip/hip_runtime.h>

// TacrolimusPK RHS: 6-compartment linear PK model, elementwise over B patients.
// Inputs (setup_inputs order): t[1], A_depot, A_gut1, A_gut2, A_gut3,
// A_central, A_peripheral, Ktr, CL, Q, Vc, Vp  (each B f32 except t).
// Output: 6 derivative arrays concatenated flat: [dA_depot | dA_gut1 | dA_gut2
// | dA_gut3 | dA_central | dA_peripheral], each B f32.
//
// Memory-bound: 44 B read + 24 B write per patient. float4 vectorization
// (16 B/lane) for coalescing; B = 2^22 is divisible by 4.

__global__ __launch_bounds__(256) void pk_rhs_kernel(
    const float4* __restrict__ Adep, const float4* __restrict__ Ag1,
    const float4* __restrict__ Ag2,  const float4* __restrict__ Ag3,
    const float4* __restrict__ Ac,   const float4* __restrict__ Ap,
    const float4* __restrict__ Ktr_, const float4* __restrict__ CL_,
    const float4* __restrict__ Q_,   const float4* __restrict__ Vc_,
    const float4* __restrict__ Vp_,
    float4* __restrict__ out, int n4)
{
    int i = blockIdx.x * blockDim.x + threadIdx.x;
    if (i >= n4) return;

    float4 ad = Adep[i], g1 = Ag1[i], g2 = Ag2[i], g3 = Ag3[i];
    float4 ac = Ac[i],   ap = Ap[i];
    float4 kt = Ktr_[i], cl = CL_[i], q = Q_[i], vc = Vc_[i], vp = Vp_[i];

    float4 o0, o1, o2, o3, o4, o5;
    const float* pad = reinterpret_cast<const float*>(&ad);
    const float* pg1 = reinterpret_cast<const float*>(&g1);
    const float* pg2 = reinterpret_cast<const float*>(&g2);
    const float* pg3 = reinterpret_cast<const float*>(&g3);
    const float* pac = reinterpret_cast<const float*>(&ac);
    const float* pap = reinterpret_cast<const float*>(&ap);
    const float* pkt = reinterpret_cast<const float*>(&kt);
    const float* pcl = reinterpret_cast<const float*>(&cl);
    const float* pq  = reinterpret_cast<const float*>(&q);
    const float* pvc = reinterpret_cast<const float*>(&vc);
    const float* pvp = reinterpret_cast<const float*>(&vp);
    float* po0 = reinterpret_cast<float*>(&o0);
    float* po1 = reinterpret_cast<float*>(&o1);
    float* po2 = reinterpret_cast<float*>(&o2);
    float* po3 = reinterpret_cast<float*>(&o3);
    float* po4 = reinterpret_cast<float*>(&o4);
    float* po5 = reinterpret_cast<float*>(&o5);

    #pragma unroll
    for (int j = 0; j < 4; ++j) {
        float ktr = pkt[j];
        float k_elim = pcl[j] / pvc[j];
        float k12    = pq[j]  / pvc[j];
        float k21    = pq[j]  / pvp[j];
        float a_dep = pad[j], a_g1 = pg1[j], a_g2 = pg2[j], a_g3 = pg3[j];
        float a_c = pac[j], a_p = pap[j];
        po0[j] = -ktr * a_dep;
        po1[j] = ktr * a_dep - ktr * a_g1;
        po2[j] = ktr * a_g1  - ktr * a_g2;
        po3[j] = ktr * a_g2  - ktr * a_g3;
        po4[j] = ktr * a_g3 - k_elim * a_c - k12 * a_c + k21 * a_p;
        po5[j] = k12 * a_c - k21 * a_p;
    }

    out[i]            = o0;
    out[i +     n4]   = o1;
    out[i + 2 * n4]   = o2;
    out[i + 3 * n4]   = o3;
    out[i + 4 * n4]   = o4;
    out[i + 5 * n4]   = o5;
}

extern "C" void kernel_launch(void* const* d_in, const int* in_sizes, int n_in,
                              void* d_out, int out_size, void* d_ws, size_t ws_size,
                              hipStream_t stream)
{
    // d_in[0] = t (unused). d_in[1..6] = states, d_in[7..11] = params.
    const int B = in_sizes[1];
    const int n4 = B / 4;

    const float4* Adep = (const float4*)d_in[1];
    const float4* Ag1  = (const float4*)d_in[2];
    const float4* Ag2  = (const float4*)d_in[3];
    const float4* Ag3  = (const float4*)d_in[4];
    const float4* Ac   = (const float4*)d_in[5];
    const float4* Ap   = (const float4*)d_in[6];
    const float4* Ktr_ = (const float4*)d_in[7];
    const float4* CL_  = (const float4*)d_in[8];
    const float4* Q_   = (const float4*)d_in[9];
    const float4* Vc_  = (const float4*)d_in[10];
    const float4* Vp_  = (const float4*)d_in[11];

    dim3 block(256);
    dim3 grid((n4 + 255) / 256);
    pk_rhs_kernel<<<grid, block, 0, stream>>>(
        Adep, Ag1, Ag2, Ag3, Ac, Ap, Ktr_, CL_, Q_, Vc_, Vp_,
        (float4*)d_out, n4);
}

// Round 2
// 45.377 us; speedup vs baseline: 1.1155x; 1.1155x over previous
//
#include <hip/hip_runtime.h>

// TacrolimusPK RHS: 6-compartment linear PK model, elementwise over B patients.
// Inputs (setup_inputs order): t[1], A_depot, A_gut1, A_gut2, A_gut3,
// A_central, A_peripheral, Ktr, CL, Q, Vc, Vp  (each B f32 except t).
// Output: 6 derivative arrays concatenated flat, each B f32.
//
// Memory-bound: 44 B read + 24 B write per patient (285 MB total).
// float4 (16 B/lane) loads for coalescing. Outputs use NON-TEMPORAL stores:
// the 101 MB write stream would otherwise evict the 184 MB input set from the
// 256 MB Infinity Cache between graph replays; nt stores keep inputs
// L3-resident so only writes pay HBM latency/BW.

typedef float f32x4 __attribute__((ext_vector_type(4)));

__global__ __launch_bounds__(256) void pk_rhs_kernel(
    const f32x4* __restrict__ Adep, const f32x4* __restrict__ Ag1,
    const f32x4* __restrict__ Ag2,  const f32x4* __restrict__ Ag3,
    const f32x4* __restrict__ Ac,   const f32x4* __restrict__ Ap,
    const f32x4* __restrict__ Ktr_, const f32x4* __restrict__ CL_,
    const f32x4* __restrict__ Q_,   const f32x4* __restrict__ Vc_,
    const f32x4* __restrict__ Vp_,
    f32x4* __restrict__ out, int n4)
{
    int i = blockIdx.x * blockDim.x + threadIdx.x;
    if (i >= n4) return;

    f32x4 ad = Adep[i], g1 = Ag1[i], g2 = Ag2[i], g3 = Ag3[i];
    f32x4 ac = Ac[i],   ap = Ap[i];
    f32x4 kt = Ktr_[i], cl = CL_[i], q = Q_[i], vc = Vc_[i], vp = Vp_[i];

    // element-wise vector math (compiler maps to packed/scalar VALU)
    f32x4 k_elim = cl / vc;
    f32x4 k12    = q  / vc;
    f32x4 k21    = q  / vp;

    f32x4 o0 = -kt * ad;
    f32x4 o1 = kt * ad - kt * g1;
    f32x4 o2 = kt * g1 - kt * g2;
    f32x4 o3 = kt * g2 - kt * g3;
    f32x4 o4 = kt * g3 - k_elim * ac - k12 * ac + k21 * ap;
    f32x4 o5 = k12 * ac - k21 * ap;

    __builtin_nontemporal_store(o0, out + i);
    __builtin_nontemporal_store(o1, out + i +     n4);
    __builtin_nontemporal_store(o2, out + i + 2 * n4);
    __builtin_nontemporal_store(o3, out + i + 3 * n4);
    __builtin_nontemporal_store(o4, out + i + 4 * n4);
    __builtin_nontemporal_store(o5, out + i + 5 * n4);
}

extern "C" void kernel_launch(void* const* d_in, const int* in_sizes, int n_in,
                              void* d_out, int out_size, void* d_ws, size_t ws_size,
                              hipStream_t stream)
{
    // d_in[0] = t (unused). d_in[1..6] = states, d_in[7..11] = params.
    const int B = in_sizes[1];
    const int n4 = B / 4;

    const f32x4* Adep = (const f32x4*)d_in[1];
    const f32x4* Ag1  = (const f32x4*)d_in[2];
    const f32x4* Ag2  = (const f32x4*)d_in[3];
    const f32x4* Ag3  = (const f32x4*)d_in[4];
    const f32x4* Ac   = (const f32x4*)d_in[5];
    const f32x4* Ap   = (const f32x4*)d_in[6];
    const f32x4* Ktr_ = (const f32x4*)d_in[7];
    const f32x4* CL_  = (const f32x4*)d_in[8];
    const f32x4* Q_   = (const f32x4*)d_in[9];
    const f32x4* Vc_  = (const f32x4*)d_in[10];
    const f32x4* Vp_  = (const f32x4*)d_in[11];

    dim3 block(256);
    dim3 grid((n4 + 255) / 256);
    pk_rhs_kernel<<<grid, block, 0, stream>>>(
        Adep, Ag1, Ag2, Ag3, Ac, Ap, Ktr_, CL_, Q_, Vc_, Vp_,
        (f32x4*)d_out, n4);
}